// Round 6
// baseline (124.713 us; speedup 1.0000x reference)
//
#include <hip/hip_runtime.h>
#include <hip/hip_bf16.h>
#include <math.h>

// Problem constants
#define MM 12544   // 64 * 196 patches
#define KK 768     // 16*16*3
#define NN 768     // embedding dim
// LDS-free GEMM: BM=64, BN=256, 4 waves 1x4 in N (each wave 64x64 output).
// A and B are pre-packed into FRAGMENT-LANE-MAJOR layout: one MFMA fragment
// (16 rows/cols x 32 k, 64 lanes x 16B) = one contiguous 1KB chunk.
// The GEMM loads fragments global->register directly: no LDS, no barriers,
// no forced vmcnt(0) drains. TWO-deep register prefetch: fragment loads for
// ks+2 issue after the MFMA cluster of ks (~620 cy in flight before their
// vmcnt wait -> covers L2 latency).
// R6: pack_kernel gets an XCD-chunked bijective swizzle (4992 = 8*624) so
// all 24 ks-blocks of one mt (same ~196KB image slice) land on ONE XCD:
// the per-ks 128B-of-192B partial reads then dedupe in that XCD's L2
// instead of being re-fetched from HBM by other XCDs.
#define BM 64
#define BN 256
#define NKS 24             // KK / 32 k-steps
#define MT 196             // MM/BM
#define NT 3               // NN/BN
#define N64 12             // NN/64 wave-column groups

#define A_BLOCKS (MT * NKS)    // 4704
#define W_BLOCKS (N64 * NKS)   // 288
#define PACK_BLOCKS (A_BLOCKS + W_BLOCKS)   // 4992 = 8 * 624
#define FRAG_BYTES 1024        // 64 lanes x 16B
#define KSTRIDE (4 * FRAG_BYTES)          // per-ks: 4 frags = 4KB
#define PANEL_BYTES (NKS * KSTRIDE)       // 96KB per 64-row/col panel

typedef __bf16 v8bf __attribute__((ext_vector_type(8)));
typedef float  v4f  __attribute__((ext_vector_type(4)));

// ---------------------------------------------------------------------------
// Pack: im2col A and transpose W into fragment-lane-major bf16 chunks.
// A chunk id: ((mt*24 + ks)*4 + mi)*64 + lane ; lane l = (k8=l>>4, row=l&15)
//   holds A[mt*64 + mi*16 + (l&15)][ks*32 + (l>>4)*8 .. +8]
// W chunk id: ((n64*24 + ks)*4 + ni)*64 + lane
//   holds W[ks*32 + (l>>4)*8 .. +8][n64*64 + ni*16 + (l&15)]
// Writes perfectly coalesced (chunk addr = base + tid*16).
// ---------------------------------------------------------------------------
__global__ __launch_bounds__(256) void pack_kernel(const float* __restrict__ img,
                                                   const float* __restrict__ w,
                                                   __hip_bfloat16* __restrict__ apack,
                                                   __hip_bfloat16* __restrict__ wpack) {
    // XCD-chunked bijective swizzle: 4992 blocks, q = 624 per XCD.
    // Hardware id h round-robins XCDs (h&7); logical u is contiguous per XCD,
    // and u/NKS = mt is constant across 24 consecutive u -> one image slice
    // per XCD L2 window.
    const int h = blockIdx.x;
    const int u = (h & 7) * (PACK_BLOCKS / 8) + (h >> 3);

    const int tid  = threadIdx.x;
    const int l    = tid & 63;
    const int fi   = tid >> 6;      // mi or ni (0..3)
    const int l_lo = l & 15;        // row / col within fragment
    const int l_hi = l >> 4;        // 8-k group within 32

    union { __hip_bfloat16 hh[8]; uint4 uu; } o;

    if (u < A_BLOCKS) {
        const int mt  = u / NKS;
        const int ks  = u - mt * NKS;
        const int m   = mt * 64 + fi * 16 + l_lo;   // global patch index
        const int k0  = ks * 32 + l_hi * 8;         // k within 768
        const int b   = m / 196;
        const int pm  = m - b * 196;
        const int pr  = pm / 14;
        const int pc  = pm - pr * 14;
        const int i   = k0 / 48;                    // row within patch
        const int rem = k0 - i * 48;                // 8-aligned, <=40
        const float* src = img + (size_t)(((b * 224 + pr * 16 + i) * 224 + pc * 16) * 3 + rem);
        float4 f0 = *(const float4*)src;            // 16B-aligned (rem mult of 8 floats)
        float4 f1 = *(const float4*)(src + 4);
        o.hh[0] = __float2bfloat16(f0.x); o.hh[1] = __float2bfloat16(f0.y);
        o.hh[2] = __float2bfloat16(f0.z); o.hh[3] = __float2bfloat16(f0.w);
        o.hh[4] = __float2bfloat16(f1.x); o.hh[5] = __float2bfloat16(f1.y);
        o.hh[6] = __float2bfloat16(f1.z); o.hh[7] = __float2bfloat16(f1.w);
        ((uint4*)apack)[(size_t)((mt * NKS + ks) * 4 + fi) * 64 + l] = o.uu;
    } else {
        const int bid = u - A_BLOCKS;
        const int n64 = bid / NKS;
        const int ks  = bid - n64 * NKS;
        const int col = n64 * 64 + fi * 16 + l_lo;
        const int k0  = ks * 32 + l_hi * 8;
        float f[8];
#pragma unroll
        for (int j = 0; j < 8; j++) f[j] = w[(size_t)(k0 + j) * NN + col];
#pragma unroll
        for (int j = 0; j < 8; j++) o.hh[j] = __float2bfloat16(f[j]);
        ((uint4*)wpack)[(size_t)((n64 * NKS + ks) * 4 + fi) * 64 + l] = o.uu;
    }
}

// Fast GELU: 0.5x(1+tanh(0.79788456(x+0.044715x^3))) = x * E/(E+1), E=e^{2t}.
// v_exp + v_rcp; max deviation from exact erf-GELU ~3e-3 << 0.103 threshold.
__device__ __forceinline__ float gelu_fast(float x) {
    float t2 = 1.5957691216057308f * x * (1.0f + 0.044715f * x * x);  // 2t
    float e  = __expf(t2);
    float r  = __builtin_amdgcn_rcpf(e + 1.0f);
    return x - x * r;   // x*(1 - 1/(E+1)) = x*E/(E+1)
}

// ---------------------------------------------------------------------------
// LDS-free MFMA GEMM + bias + fast GELU, 2-deep register pipeline.
// 64x256 tile, 4 waves 1x4 in N. A-frags 4x-duplicated across waves -> L1
// hits; B-frags wave-private. XCD chunked swizzle (bijective for 588):
// the 3 nt-blocks of one mt share an XCD's L2 (A-panels + B fit in 4MB).
// ---------------------------------------------------------------------------
__global__ __launch_bounds__(256, 3) void gemm_reg(const __hip_bfloat16* __restrict__ apack,
                                                   const __hip_bfloat16* __restrict__ wpack,
                                                   const float* __restrict__ bias,
                                                   float* __restrict__ out) {
    const int h   = blockIdx.x;
    const int xcd = h & 7;
    const int jj  = h >> 3;
    const int u   = (xcd < 4 ? xcd * 74 : 296 + (xcd - 4) * 73) + jj;
    const int nt  = u % 3;
    const int mt  = u / 3;

    const int tid  = threadIdx.x;
    const int lane = tid & 63;
    const int wave = tid >> 6;
    const int col  = lane & 15;
    const int quad = lane >> 4;

    const char* pA = (const char*)apack + (size_t)mt * PANEL_BYTES + lane * 16;
    const char* pB = (const char*)wpack + (size_t)(nt * 4 + wave) * PANEL_BYTES + lane * 16;

    v4f acc[4][4];
    const v4f vzero = {0.f, 0.f, 0.f, 0.f};
#pragma unroll
    for (int a = 0; a < 4; a++)
#pragma unroll
        for (int c = 0; c < 4; c++) acc[a][c] = vzero;

    v8bf aR[2][4], bR[2][4];
    // ---- prologue: preload ks = 0 (buf0) and ks = 1 (buf1), B first ----
#pragma unroll
    for (int ni = 0; ni < 4; ni++) {
        bR[0][ni] = *(const v8bf*)(pB + ni * FRAG_BYTES);
        bR[1][ni] = *(const v8bf*)(pB + KSTRIDE + ni * FRAG_BYTES);
    }
#pragma unroll
    for (int mi = 0; mi < 4; mi++) {
        aR[0][mi] = *(const v8bf*)(pA + mi * FRAG_BYTES);
        aR[1][mi] = *(const v8bf*)(pA + KSTRIDE + mi * FRAG_BYTES);
    }

    // ---- main loop: MFMA(ks) then issue loads for ks+2 into buf[ks&1].
    // Loads sit in flight across ~2 MFMA clusters before their vmcnt wait.
    // B issued before A: B is L2/HBM (longer latency), A is mostly L1-hot.
#pragma unroll
    for (int ks = 0; ks < NKS; ks++) {
        const int cur = ks & 1;          // literal after full unroll
        __builtin_amdgcn_s_setprio(1);
#pragma unroll
        for (int mi = 0; mi < 4; mi++)
#pragma unroll
            for (int ni = 0; ni < 4; ni++)
                acc[mi][ni] = __builtin_amdgcn_mfma_f32_16x16x32_bf16(
                    aR[cur][mi], bR[cur][ni], acc[mi][ni], 0, 0, 0);
        __builtin_amdgcn_s_setprio(0);
        if (ks + 2 < NKS) {
            const char* qA = pA + (size_t)(ks + 2) * KSTRIDE;
            const char* qB = pB + (size_t)(ks + 2) * KSTRIDE;
#pragma unroll
            for (int ni = 0; ni < 4; ni++)
                bR[cur][ni] = *(const v8bf*)(qB + ni * FRAG_BYTES);
#pragma unroll
            for (int mi = 0; mi < 4; mi++)
                aR[cur][mi] = *(const v8bf*)(qA + mi * FRAG_BYTES);
        }
    }

    // ---- epilogue: bias + fast GELU, coalesced fp32 stores ----
#pragma unroll
    for (int ni = 0; ni < 4; ni++) {
        int n    = nt * BN + wave * 64 + ni * 16 + col;
        float bv = bias[n];
#pragma unroll
        for (int mi = 0; mi < 4; mi++) {
            int rowb = mt * BM + mi * 16 + quad * 4;
            float* po = out + (size_t)rowb * NN + n;
#pragma unroll
            for (int rg = 0; rg < 4; rg++) {
                float x = acc[mi][ni][rg] + bv;
                po[(size_t)rg * NN] = gelu_fast(x);
            }
        }
    }
}

extern "C" void kernel_launch(void* const* d_in, const int* in_sizes, int n_in,
                              void* d_out, int out_size, void* d_ws, size_t ws_size,
                              hipStream_t stream) {
    const float* img   = (const float*)d_in[0];   // [64,224,224,3]
    const float* wproj = (const float*)d_in[1];   // [768,768]
    const float* bias  = (const float*)d_in[2];   // [768]
    float* out = (float*)d_out;                   // [64,196,768]

    __hip_bfloat16* apack = (__hip_bfloat16*)d_ws;                        // 19,267,584 B
    __hip_bfloat16* wpack = (__hip_bfloat16*)((char*)d_ws + (size_t)MM * KK * 2);
    // total ws need: 20,447,232 B

    pack_kernel<<<dim3(PACK_BLOCKS), dim3(256), 0, stream>>>(
        img, wproj, apack, wpack);
    gemm_reg<<<dim3(MT * NT), dim3(256), 0, stream>>>(apack, wpack, bias, out);
}

// Round 7
// 120.476 us; speedup vs baseline: 1.0352x; 1.0352x over previous
//
#include <hip/hip_runtime.h>
#include <hip/hip_bf16.h>
#include <math.h>

// Problem constants
#define MM 12544   // 64 * 196 patches
#define KK 768     // 16*16*3
#define NN 768     // embedding dim
// LDS-free GEMM: BM=64, BN=256, 4 waves 1x4 in N (each wave 64x64 output).
// A and B are pre-packed into FRAGMENT-LANE-MAJOR layout: one MFMA fragment
// (16 rows/cols x 32 k, 64 lanes x 16B) = one contiguous 1KB chunk.
// The GEMM loads fragments global->register directly: no LDS, no barriers,
// no forced vmcnt(0) drains. TWO-deep register prefetch (R5 structure,
// session best). R7: READ-ONCE pack -- each pack thread reads one full
// 48-float patch-row run (12x contiguous float4, zero partial-sector
// overfetch; R5's per-ks blocks read 128B of each 192B span and re-fetched
// the rest from another XCD), then scatter-writes 6 bf16 k-groups.
#define BM 64
#define BN 256
#define NKS 24             // KK / 32 k-steps
#define MT 196             // MM/BM
#define NT 3               // NN/BN
#define N64 12             // NN/64 wave-column groups

#define A2_BLOCKS (MT * 4)     // 784: one block per (mt, row-quarter)
#define W_BLOCKS (N64 * NKS)   // 288
#define FRAG_BYTES 1024        // 64 lanes x 16B
#define KSTRIDE (4 * FRAG_BYTES)          // per-ks: 4 frags = 4KB
#define PANEL_BYTES (NKS * KSTRIDE)       // 96KB per 64-row/col panel

typedef __bf16 v8bf __attribute__((ext_vector_type(8)));
typedef float  v4f  __attribute__((ext_vector_type(4)));

// ---------------------------------------------------------------------------
// Pack: im2col A (read-once) and transpose W into fragment-lane-major chunks.
// A chunk id: ((mt*24 + ks)*4 + fi)*64 + lane ; lane l = (k8=l>>4, row=l&15)
//   holds A[mt*64 + fi*16 + (l&15)][ks*32 + (l>>4)*8 .. +8]
// A-blocks: blk = mt*4 + c. Thread (r = tid&63, il = tid>>6) reads patch
//   m = mt*64+r, row i = c*4+il: 48 contiguous floats (one im2col row-run),
//   emits 6 groups G = i*6+j -> (ks = G>>2, l_hi = G&3).
// W chunk id: ((n64*24 + ks)*4 + ni)*64 + lane  (as R5, unchanged).
// ---------------------------------------------------------------------------
__global__ __launch_bounds__(256) void pack_kernel(const float* __restrict__ img,
                                                   const float* __restrict__ w,
                                                   __hip_bfloat16* __restrict__ apack,
                                                   __hip_bfloat16* __restrict__ wpack) {
    const int tid = threadIdx.x;

    if (blockIdx.x < A2_BLOCKS) {
        const int blk = blockIdx.x;
        const int mt  = blk >> 2;          // 0..195
        const int c   = blk & 3;           // row-quarter
        const int r   = tid & 63;          // patch within tile
        const int il  = tid >> 6;          // 0..3 (wave-uniform)
        const int i   = c * 4 + il;        // patch row 0..15
        const int m   = mt * 64 + r;
        const int b   = m / 196;
        const int pm  = m - b * 196;
        const int pr  = pm / 14;
        const int pc  = pm - pr * 14;
        const float* src = img + (size_t)(((b * 224 + pr * 16 + i) * 224 + pc * 16) * 3);
        float4 f[12];
#pragma unroll
        for (int ld = 0; ld < 12; ld++) f[ld] = ((const float4*)src)[ld];

        const int fi   = r >> 4;
        const int l_lo = r & 15;
        // chunk base for (mt, ks=0, fi), this lane's slot l_lo
        uint4* dst = (uint4*)apack + ((size_t)(mt * 24) * 4 + fi) * 64 + l_lo;
#pragma unroll
        for (int j = 0; j < 6; j++) {
            const int G  = i * 6 + j;      // global 8-group index 0..95
            const int ks = G >> 2;
            const int lh = G & 3;
            union { __hip_bfloat16 hh[8]; uint4 uu; } o;
            o.hh[0] = __float2bfloat16(f[2*j].x);   o.hh[1] = __float2bfloat16(f[2*j].y);
            o.hh[2] = __float2bfloat16(f[2*j].z);   o.hh[3] = __float2bfloat16(f[2*j].w);
            o.hh[4] = __float2bfloat16(f[2*j+1].x); o.hh[5] = __float2bfloat16(f[2*j+1].y);
            o.hh[6] = __float2bfloat16(f[2*j+1].z); o.hh[7] = __float2bfloat16(f[2*j+1].w);
            dst[(size_t)ks * 256 + lh * 16] = o.uu;   // +ks*4*64 + lh*16
        }
    } else {
        const int bid = blockIdx.x - A2_BLOCKS;
        const int gid = bid * 256 + tid;   // 0 .. 288*256-1
        const int l    = gid & 63;
        const int fi   = (gid >> 6) & 3;
        const int wb   = gid >> 8;         // 0..287
        const int n64  = wb / NKS;
        const int ks   = wb - n64 * NKS;
        const int col  = n64 * 64 + fi * 16 + (l & 15);
        const int k0   = ks * 32 + (l >> 4) * 8;
        union { __hip_bfloat16 hh[8]; uint4 uu; } o;
#pragma unroll
        for (int j = 0; j < 8; j++) o.hh[j] = __float2bfloat16(w[(size_t)(k0 + j) * NN + col]);
        ((uint4*)wpack)[(size_t)((n64 * NKS + ks) * 4 + fi) * 64 + l] = o.uu;
    }
}

// Fast GELU: 0.5x(1+tanh(0.79788456(x+0.044715x^3))) = x * E/(E+1), E=e^{2t}.
// v_exp + v_rcp; max deviation from exact erf-GELU ~3e-3 << 0.103 threshold.
__device__ __forceinline__ float gelu_fast(float x) {
    float t2 = 1.5957691216057308f * x * (1.0f + 0.044715f * x * x);  // 2t
    float e  = __expf(t2);
    float r  = __builtin_amdgcn_rcpf(e + 1.0f);
    return x - x * r;   // x*(1 - 1/(E+1)) = x*E/(E+1)
}

// ---------------------------------------------------------------------------
// LDS-free MFMA GEMM + bias + fast GELU, 2-deep register pipeline.
// (R5 exact.) 64x256 tile, 4 waves 1x4 in N. A-frags 4x-duplicated across
// waves -> L1 hits; B-frags wave-private. XCD chunked swizzle (bijective
// for 588): the 3 nt-blocks of one mt share an XCD's L2.
// ---------------------------------------------------------------------------
__global__ __launch_bounds__(256, 3) void gemm_reg(const __hip_bfloat16* __restrict__ apack,
                                                   const __hip_bfloat16* __restrict__ wpack,
                                                   const float* __restrict__ bias,
                                                   float* __restrict__ out) {
    const int h   = blockIdx.x;
    const int xcd = h & 7;
    const int jj  = h >> 3;
    const int u   = (xcd < 4 ? xcd * 74 : 296 + (xcd - 4) * 73) + jj;
    const int nt  = u % 3;
    const int mt  = u / 3;

    const int tid  = threadIdx.x;
    const int lane = tid & 63;
    const int wave = tid >> 6;
    const int col  = lane & 15;
    const int quad = lane >> 4;

    const char* pA = (const char*)apack + (size_t)mt * PANEL_BYTES + lane * 16;
    const char* pB = (const char*)wpack + (size_t)(nt * 4 + wave) * PANEL_BYTES + lane * 16;

    v4f acc[4][4];
    const v4f vzero = {0.f, 0.f, 0.f, 0.f};
#pragma unroll
    for (int a = 0; a < 4; a++)
#pragma unroll
        for (int c = 0; c < 4; c++) acc[a][c] = vzero;

    v8bf aR[2][4], bR[2][4];
    // ---- prologue: preload ks = 0 (buf0) and ks = 1 (buf1) ----
#pragma unroll
    for (int mi = 0; mi < 4; mi++) {
        aR[0][mi] = *(const v8bf*)(pA + mi * FRAG_BYTES);
        aR[1][mi] = *(const v8bf*)(pA + KSTRIDE + mi * FRAG_BYTES);
    }
#pragma unroll
    for (int ni = 0; ni < 4; ni++) {
        bR[0][ni] = *(const v8bf*)(pB + ni * FRAG_BYTES);
        bR[1][ni] = *(const v8bf*)(pB + KSTRIDE + ni * FRAG_BYTES);
    }

    // ---- main loop: MFMA(ks) then issue loads for ks+2 into buf[ks&1].
    // Loads sit in flight across ~2 MFMA clusters before their vmcnt wait.
#pragma unroll
    for (int ks = 0; ks < NKS; ks++) {
        const int cur = ks & 1;          // literal after full unroll
        __builtin_amdgcn_s_setprio(1);
#pragma unroll
        for (int mi = 0; mi < 4; mi++)
#pragma unroll
            for (int ni = 0; ni < 4; ni++)
                acc[mi][ni] = __builtin_amdgcn_mfma_f32_16x16x32_bf16(
                    aR[cur][mi], bR[cur][ni], acc[mi][ni], 0, 0, 0);
        __builtin_amdgcn_s_setprio(0);
        if (ks + 2 < NKS) {
            const char* qA = pA + (size_t)(ks + 2) * KSTRIDE;
            const char* qB = pB + (size_t)(ks + 2) * KSTRIDE;
#pragma unroll
            for (int mi = 0; mi < 4; mi++)
                aR[cur][mi] = *(const v8bf*)(qA + mi * FRAG_BYTES);
#pragma unroll
            for (int ni = 0; ni < 4; ni++)
                bR[cur][ni] = *(const v8bf*)(qB + ni * FRAG_BYTES);
        }
    }

    // ---- epilogue: bias + fast GELU, coalesced fp32 stores ----
#pragma unroll
    for (int ni = 0; ni < 4; ni++) {
        int n    = nt * BN + wave * 64 + ni * 16 + col;
        float bv = bias[n];
#pragma unroll
        for (int mi = 0; mi < 4; mi++) {
            int rowb = mt * BM + mi * 16 + quad * 4;
            float* po = out + (size_t)rowb * NN + n;
#pragma unroll
            for (int rg = 0; rg < 4; rg++) {
                float x = acc[mi][ni][rg] + bv;
                po[(size_t)rg * NN] = gelu_fast(x);
            }
        }
    }
}

extern "C" void kernel_launch(void* const* d_in, const int* in_sizes, int n_in,
                              void* d_out, int out_size, void* d_ws, size_t ws_size,
                              hipStream_t stream) {
    const float* img   = (const float*)d_in[0];   // [64,224,224,3]
    const float* wproj = (const float*)d_in[1];   // [768,768]
    const float* bias  = (const float*)d_in[2];   // [768]
    float* out = (float*)d_out;                   // [64,196,768]

    __hip_bfloat16* apack = (__hip_bfloat16*)d_ws;                        // 19,267,584 B
    __hip_bfloat16* wpack = (__hip_bfloat16*)((char*)d_ws + (size_t)MM * KK * 2);
    // total ws need: 20,447,232 B

    pack_kernel<<<dim3(A2_BLOCKS + W_BLOCKS), dim3(256), 0, stream>>>(
        img, wproj, apack, wpack);
    gemm_reg<<<dim3(MT * NT), dim3(256), 0, stream>>>(apack, wpack, bias, out);
}